// Round 11
// baseline (490.998 us; speedup 1.0000x reference)
//
#include <hip/hip_runtime.h>
#include <hip/hip_fp16.h>
#include <math.h>

#define NN 50000
#define NE 800000
#define FEAT 64
#define HID 4096
#define NEG_SLOPE 0.2f
#define T_STEPS 3
#define SLOTS 64                      // per-dst max in-degree (mean 16, P(>=64)~2e-18)
#define NB 391                        // coarse buckets per step: dst>>7
#define CAP 2560                      // per coarse-region capacity (mean 2048, ~11 sigma)
#define CHUNK 2048
#define CHUNKS_PER_STEP ((NE + CHUNK - 1) / CHUNK)   // 391
#define FEAT_BLKS ((NN + 255) / 256)                 // 196
#define PART_BLKS (T_STEPS * CHUNKS_PER_STEP)        // 1173
#define LSTM_BLKS (HID / 4)                          // 1024

extern __shared__ char smem_dyn[];

__device__ __forceinline__ int pack_half2(float a, float b) {
    __half2 h = __floats2half2_rn(a, b);
    return *(int*)&h;
}
__device__ __forceinline__ float2 unpack_half2(int v) {
    __half2 h = *(__half2*)&v;
    return __half22float2(h);
}

// ---------------- section bodies (blockIdx-uniform branches) ----------------

__device__ void dev_wsum(int wid, int tid, const float* __restrict__ node_embs,
                         const float* __restrict__ mask, float* __restrict__ sumexp,
                         float* __restrict__ inp_acc) {
    int t = wid >> 8;
    int blk = wid & 255;
    const float* x_t = node_embs + (size_t)t * NN * FEAT;
    const float* mask_t = mask + (size_t)t * NN;
    int lane = tid & 63, wib = tid >> 6;
    int gw = blk * 4 + wib;
    float acc = 0.f, se = 0.f;
    for (int n = gw; n < NN; n += 1024) {
        float w = expf(mask_t[n]);
        acc += w * x_t[(size_t)n * FEAT + lane];
        se += w;
    }
    float (*sacc)[FEAT] = (float (*)[FEAT])smem_dyn;
    sacc[wib][lane] = acc;
    __syncthreads();
    if (wib == 0)
        atomicAdd(&inp_acc[t * FEAT + lane],
                  sacc[0][lane] + sacc[1][lane] + sacc[2][lane] + sacc[3][lane]);
    if (lane == 0) atomicAdd(&sumexp[t], se);
}

// coarse counting-sort of a CHUNK-edge slice; LDS = 16384(stag)+4*1564+1024 = 23664 B
__device__ void dev_part(int pbid, int tid, const int* __restrict__ edge_index,
                         const float* __restrict__ edge_weight,
                         int* __restrict__ coarse_cnt, int2* __restrict__ coarse) {
    int t = pbid / CHUNKS_PER_STEP;
    int ch = pbid % CHUNKS_PER_STEP;
    int e0 = ch * CHUNK;
    int eN = (e0 + CHUNK <= NE) ? CHUNK : (NE - e0);
    const int* src = edge_index + (size_t)t * 2 * NE;
    const int* dst = src + NE;
    const float* ew = edge_weight + (size_t)t * NE;
    int2* stag  = (int2*)smem_dyn;                    // 16384 B
    int* hist   = (int*)(smem_dyn + 16384);           // 1564
    int* offs   = (int*)(smem_dyn + 17948);
    int* baseg  = (int*)(smem_dyn + 19512);
    int* cursor = (int*)(smem_dyn + 21076);
    int* sc     = (int*)(smem_dyn + 22640);           // 1024
    for (int i = tid; i < NB; i += 256) hist[i] = 0;
    __syncthreads();
    for (int k = tid; k < eN; k += 256) atomicAdd(&hist[dst[e0 + k] >> 7], 1);
    __syncthreads();
    int a0 = (2 * tid < NB) ? hist[2 * tid] : 0;
    int a1 = (2 * tid + 1 < NB) ? hist[2 * tid + 1] : 0;
    sc[tid] = a0 + a1;
    __syncthreads();
    for (int off = 1; off < 256; off <<= 1) {
        int v = (tid >= off) ? sc[tid - off] : 0;
        __syncthreads();
        sc[tid] += v;
        __syncthreads();
    }
    int excl = (tid == 0) ? 0 : sc[tid - 1];
    if (2 * tid < NB)     { offs[2 * tid] = excl;          cursor[2 * tid] = excl; }
    if (2 * tid + 1 < NB) { offs[2 * tid + 1] = excl + a0; cursor[2 * tid + 1] = excl + a0; }
    __syncthreads();
    for (int k = tid; k < eN; k += 256) {
        int d = dst[e0 + k], s = src[e0 + k];
        float wv = ew[e0 + k];
        int cb = d >> 7, doff = d & 127;
        int p = atomicAdd(&cursor[cb], 1);
        stag[p] = make_int2(s | (doff << 16) | (cb << 23), __float_as_int(wv));
    }
    __syncthreads();
    for (int cb = tid; cb < NB; cb += 256) {
        int cnum = hist[cb];
        baseg[cb] = cnum ? atomicAdd(&coarse_cnt[t * NB + cb], cnum) : 0;
    }
    __syncthreads();
    for (int j = tid; j < eN; j += 256) {
        int2 r = stag[j];
        int cb = ((unsigned)r.x) >> 23;
        int gpos = baseg[cb] + (j - offs[cb]);
        if (gpos < CAP)
            coarse[((size_t)(t * NB + cb)) * CAP + gpos] = r;
    }
}

// one wave per unit u; rows {u,u+H,u+2H,u+3H}; CVT: read fp32 Whh, emit fp16 copy
template <bool CVT>
__device__ void dev_lstm(int lbid, int tid,
                         const float* __restrict__ Wih, const float* __restrict__ Whh,
                         __half* __restrict__ Whh_h,
                         const float* __restrict__ bih, const float* __restrict__ bhh,
                         const float* __restrict__ inp_acc_t, const float* __restrict__ sumexp_t,
                         const float* __restrict__ h_old, float* __restrict__ h_new,
                         float* __restrict__ c, float* __restrict__ Wbuf_lt) {
    int lane = tid & 63;
    int u = (lbid * 256 + tid) >> 6;
    if (u >= HID) return;
    float inp_l = inp_acc_t[lane] / (*sumexp_t);
    const float4* h4 = (const float4*)h_old;
    float g4[4];
    #pragma unroll
    for (int gi = 0; gi < 4; ++gi) {
        int row = u + gi * HID;
        float acc = 0.f;
        if (CVT) {
            const float4* wr = (const float4*)(Whh + (size_t)row * HID);
            int2* wh = (int2*)(Whh_h + (size_t)row * HID);
            #pragma unroll
            for (int cc = 0; cc < 16; ++cc) {
                float4 w = wr[cc * 64 + lane];
                float4 hv = h4[cc * 64 + lane];
                acc += w.x * hv.x + w.y * hv.y + w.z * hv.z + w.w * hv.w;
                int2 p;
                p.x = pack_half2(w.x, w.y);
                p.y = pack_half2(w.z, w.w);
                wh[cc * 64 + lane] = p;
            }
        } else {
            const int4* wr = (const int4*)(Whh_h + (size_t)row * HID);
            #pragma unroll
            for (int cc = 0; cc < 8; ++cc) {
                int4 w = wr[cc * 64 + lane];
                float2 wa = unpack_half2(w.x), wb = unpack_half2(w.y);
                float2 wc = unpack_half2(w.z), wd = unpack_half2(w.w);
                float4 hv0 = h4[(cc * 64 + lane) * 2];
                float4 hv1 = h4[(cc * 64 + lane) * 2 + 1];
                acc += wa.x * hv0.x + wa.y * hv0.y + wb.x * hv0.z + wb.y * hv0.w;
                acc += wc.x * hv1.x + wc.y * hv1.y + wd.x * hv1.z + wd.y * hv1.w;
            }
        }
        acc += Wih[(size_t)row * FEAT + lane] * inp_l;
        #pragma unroll
        for (int off = 32; off > 0; off >>= 1) acc += __shfl_xor(acc, off, 64);
        if (lane == 0) g4[gi] = acc + bih[row] + bhh[row];
    }
    if (lane == 0) {
        float si = 1.f / (1.f + expf(-g4[0]));
        float sf = 1.f / (1.f + expf(-g4[1]));
        float so = 1.f / (1.f + expf(-g4[3]));
        float c2 = sf * c[u] + si * tanhf(g4[2]);
        float h2 = so * tanhf(c2);
        c[u] = c2; h_new[u] = h2; Wbuf_lt[u] = h2;
    }
}

// hfeat(fp16) = x @ W; al/ar = hfeat·att. LDS = 16384 + 512 = 16896 B
__device__ void dev_feat(int fbid, int tid, const float* __restrict__ x_t,
                         const float* __restrict__ Wbuf_ft, const float* __restrict__ att,
                         __half* __restrict__ hfeat_ft, float* __restrict__ al_ft,
                         float* __restrict__ ar_ft) {
    float* Wl   = (float*)smem_dyn;            // 16384 B
    float* attS = (float*)(smem_dyn + 16384);  // 512 B
    for (int i = tid; i < HID; i += 256) Wl[i] = Wbuf_ft[i];
    if (tid < 2 * FEAT) attS[tid] = att[tid];
    __syncthreads();
    int n = fbid * 256 + tid;
    if (n >= NN) return;
    float acc[FEAT];
    #pragma unroll
    for (int o = 0; o < FEAT; ++o) acc[o] = 0.f;
    const float4* x4 = (const float4*)(x_t + (size_t)n * FEAT);
    for (int k4 = 0; k4 < 16; ++k4) {
        float4 xv = x4[k4];
        const float* w0 = &Wl[(k4 * 4 + 0) * FEAT];
        const float* w1 = &Wl[(k4 * 4 + 1) * FEAT];
        const float* w2 = &Wl[(k4 * 4 + 2) * FEAT];
        const float* w3 = &Wl[(k4 * 4 + 3) * FEAT];
        #pragma unroll
        for (int o = 0; o < FEAT; ++o)
            acc[o] += xv.x * w0[o] + xv.y * w1[o] + xv.z * w2[o] + xv.w * w3[o];
    }
    float aL = 0.f, aR = 0.f;
    #pragma unroll
    for (int o = 0; o < FEAT; ++o) { aL += acc[o] * attS[o]; aR += acc[o] * attS[FEAT + o]; }
    int4* hf = (int4*)(hfeat_ft + (size_t)n * FEAT);
    #pragma unroll
    for (int i = 0; i < 8; ++i) {
        int4 v;
        v.x = pack_half2(acc[8 * i + 0], acc[8 * i + 1]);
        v.y = pack_half2(acc[8 * i + 2], acc[8 * i + 3]);
        v.z = pack_half2(acc[8 * i + 4], acc[8 * i + 5]);
        v.w = pack_half2(acc[8 * i + 6], acc[8 * i + 7]);
        hf[i] = v;
    }
    al_ft[n] = aL; ar_ft[n] = aR;
}

// fine-bin + GAT for coarse bucket cb of step t; 256 threads (4 waves × 32 rows).
// LDS = 32768(fine) + 512(fcnt) = 33280 B
__device__ void dev_gat(int t, int cb, int tid,
                        const int* __restrict__ coarse_cnt, const int2* __restrict__ coarse,
                        const float* __restrict__ al, const float* __restrict__ ar,
                        const __half* __restrict__ hfeat, float* __restrict__ out) {
    int* fine = (int*)smem_dyn;             // 128*SLOTS ints
    int* fcnt = (int*)(smem_dyn + 32768);   // 128 ints
    int n0 = cb << 7;
    for (int i = tid; i < 128; i += 256) fcnt[i] = 0;
    __syncthreads();
    int m = coarse_cnt[t * NB + cb];
    if (m > CAP) m = CAP;
    const int2* reg = coarse + ((size_t)(t * NB + cb)) * CAP;
    for (int k = tid; k < m; k += 256) {
        int2 r = reg[k];
        int doff = (r.x >> 16) & 127;
        int p = atomicAdd(&fcnt[doff], 1);
        if (p < SLOTS) {
            unsigned int eh = (unsigned int)__half_as_ushort(__float2half_rn(__int_as_float(r.y)));
            fine[doff * SLOTS + p] = (r.x & 0xffff) | (int)(eh << 16);
        }
    }
    __syncthreads();
    int lane = tid & 63, w = tid >> 6;      // 4 waves
    const float* al_t = al + (size_t)t * NN;
    const __half* hf_t = hfeat + (size_t)t * NN * FEAT;
    int sub = lane >> 4;
    int fl = (lane & 15) * 4;
    for (int doff = w; doff < 128; doff += 4) {
        int row = n0 + doff;
        if (row >= NN) break;
        int cn = fcnt[doff]; if (cn > SLOTS) cn = SLOTS;
        float ard = ar[(size_t)t * NN + row];
        float4 acc = make_float4(0.f, 0.f, 0.f, 0.f);
        float psum = 0.f;
        for (int i = sub; i < cn; i += 4) {
            int r = fine[doff * SLOTS + i];
            int s = r & 0xffff;
            float ewv = __half2float(__ushort_as_half((unsigned short)((unsigned int)r >> 16)));
            float e = al_t[s] + ard;
            e = e >= 0.f ? e : NEG_SLOPE * e;
            float p = expf(e);
            psum += p;
            float pe = p * ewv;
            int2 hv2 = *(const int2*)(hf_t + (size_t)s * FEAT + fl);
            float2 ha = unpack_half2(hv2.x), hb = unpack_half2(hv2.y);
            acc.x += pe * ha.x; acc.y += pe * ha.y;
            acc.z += pe * hb.x; acc.w += pe * hb.y;
        }
        acc.x += __shfl_xor(acc.x, 16, 64); acc.y += __shfl_xor(acc.y, 16, 64);
        acc.z += __shfl_xor(acc.z, 16, 64); acc.w += __shfl_xor(acc.w, 16, 64);
        psum  += __shfl_xor(psum, 16, 64);
        acc.x += __shfl_xor(acc.x, 32, 64); acc.y += __shfl_xor(acc.y, 32, 64);
        acc.z += __shfl_xor(acc.z, 32, 64); acc.w += __shfl_xor(acc.w, 32, 64);
        psum  += __shfl_xor(psum, 32, 64);
        float inv = 1.f / (psum + 1e-16f);
        if (sub == 0)
            *(float4*)(out + ((size_t)t * NN + row) * FEAT + fl) =
                make_float4(acc.x * inv, acc.y * inv, acc.z * inv, acc.w * inv);
    }
}

// ---------------- launch wrappers ----------------

// A: wsum for all 3 steps (768 blocks)
__global__ __launch_bounds__(256) void k_wsum_all(
    const float* __restrict__ node_embs, const float* __restrict__ mask,
    float* __restrict__ sumexp, float* __restrict__ inp_acc) {
    dev_wsum(blockIdx.x, threadIdx.x, node_embs, mask, sumexp, inp_acc);
}

// B: lstm0(cvt) [0,1024) || part [1024, 1024+PART_BLKS)
__global__ __launch_bounds__(256) void k_b(
    const int* __restrict__ edge_index, const float* __restrict__ edge_weight,
    const float* __restrict__ Wih, const float* __restrict__ Whh, __half* __restrict__ Whh_h,
    const float* __restrict__ bih, const float* __restrict__ bhh,
    const float* __restrict__ inp_acc0, const float* __restrict__ sumexp0,
    const float* __restrict__ h_old, float* __restrict__ h_new,
    float* __restrict__ c, float* __restrict__ Wbuf0,
    int* __restrict__ ccnt, int2* __restrict__ coarse) {
    if (blockIdx.x < LSTM_BLKS)
        dev_lstm<true>(blockIdx.x, threadIdx.x, Wih, Whh, Whh_h, bih, bhh,
                       inp_acc0, sumexp0, h_old, h_new, c, Wbuf0);
    else
        dev_part(blockIdx.x - LSTM_BLKS, threadIdx.x, edge_index, edge_weight, ccnt, coarse);
}

// C/D/E/F: gat [0,n_gat) || feat [n_gat, n_gat+n_feat) || lstm [rest)
__global__ __launch_bounds__(256) void k_stage(
    int n_gat, int t_gat, int n_feat,
    const int* __restrict__ ccnt, const int2* __restrict__ coarse,
    const float* __restrict__ al, const float* __restrict__ ar,
    const __half* __restrict__ hfeat, float* __restrict__ out,
    const float* __restrict__ x_ft, const float* __restrict__ Wbuf_ft,
    const float* __restrict__ att, __half* __restrict__ hfeat_ft,
    float* __restrict__ al_ft, float* __restrict__ ar_ft,
    const float* __restrict__ Wih, __half* __restrict__ Whh_h,
    const float* __restrict__ bih, const float* __restrict__ bhh,
    const float* __restrict__ inp_acc_t, const float* __restrict__ sumexp_t,
    const float* __restrict__ h_old, float* __restrict__ h_new,
    float* __restrict__ c, float* __restrict__ Wbuf_lt) {
    int bid = blockIdx.x;
    if (bid < n_gat)
        dev_gat(t_gat, bid, threadIdx.x, ccnt, coarse, al, ar, hfeat, out);
    else if (bid < n_gat + n_feat)
        dev_feat(bid - n_gat, threadIdx.x, x_ft, Wbuf_ft, att, hfeat_ft, al_ft, ar_ft);
    else
        dev_lstm<false>(bid - n_gat - n_feat, threadIdx.x, Wih, nullptr, Whh_h, bih, bhh,
                        inp_acc_t, sumexp_t, h_old, h_new, c, Wbuf_lt);
}

extern "C" void kernel_launch(void* const* d_in, const int* in_sizes, int n_in,
                              void* d_out, int out_size, void* d_ws, size_t ws_size,
                              hipStream_t stream) {
    const float* node_embs   = (const float*)d_in[0];
    const float* mask        = (const float*)d_in[1];
    const int*   edge_index  = (const int*)d_in[2];
    const float* edge_weight = (const float*)d_in[3];
    const float* Wih         = (const float*)d_in[4];
    const float* Whh         = (const float*)d_in[5];
    const float* bih         = (const float*)d_in[6];
    const float* bhh         = (const float*)d_in[7];
    const float* W0          = (const float*)d_in[8];
    const float* att         = (const float*)d_in[9];
    float* out = (float*)d_out;
    float* ws  = (float*)d_ws;

    // workspace layout (4B units), total ~179 MB
    float*  h0       = ws;                          // [0, 4096)
    float*  h1       = ws + 4096;                   // [4096, 8192)
    float*  c_state  = ws + 8192;                   // [8192, 12288)  -- zero region start
    float*  sumexp   = ws + 12288;                  // 4
    float*  inp_acc  = ws + 12292;                  // 192
    int*    ccnt     = (int*)(ws + 12484);          // 1173 -> zero region end 13657
    float*  Wbuf     = ws + 13660;                  // 3*4096
    float*  al       = ws + 25948;                  // 3*50000
    float*  ar       = ws + 175948;                 // 3*50000
    int2*   coarse   = (int2*)(ws + 325948);        // 3*NB*CAP int2 = 24 MB
    __half* Whh_h    = (__half*)(ws + 6331708);     // 67.1M halves = 128 MB
    __half* hfeat    = (__half*)(ws + 39886140);    // 9.6M halves = 19.2 MB

    hipMemcpyAsync(h0, W0, HID * sizeof(float), hipMemcpyDeviceToDevice, stream);
    hipMemsetAsync(ws + 8192, 0, (size_t)(13657 - 8192) * sizeof(float), stream);

    // A: all wsums
    k_wsum_all<<<T_STEPS * 256, 256, 1024, stream>>>(node_embs, mask, sumexp, inp_acc);

    // B: lstm0 (fp32 Whh read + fp16 emit) || part for all steps
    k_b<<<LSTM_BLKS + PART_BLKS, 256, 23680, stream>>>(
        edge_index, edge_weight, Wih, Whh, Whh_h, bih, bhh,
        inp_acc + 0 * FEAT, sumexp + 0, h0, h1, c_state, Wbuf + 0 * HID, ccnt, coarse);

    // C: feat0 || lstm1
    k_stage<<<FEAT_BLKS + LSTM_BLKS, 256, 16896, stream>>>(
        0, 0, FEAT_BLKS,
        ccnt, coarse, al, ar, hfeat, out,
        node_embs + (size_t)0 * NN * FEAT, Wbuf + 0 * HID, att,
        hfeat + (size_t)0 * NN * FEAT, al + 0 * NN, ar + 0 * NN,
        Wih, Whh_h, bih, bhh, inp_acc + 1 * FEAT, sumexp + 1, h1, h0, c_state, Wbuf + 1 * HID);

    // D: gat0 || feat1 || lstm2
    k_stage<<<NB + FEAT_BLKS + LSTM_BLKS, 256, 33280, stream>>>(
        NB, 0, FEAT_BLKS,
        ccnt, coarse, al, ar, hfeat, out,
        node_embs + (size_t)1 * NN * FEAT, Wbuf + 1 * HID, att,
        hfeat + (size_t)1 * NN * FEAT, al + 1 * NN, ar + 1 * NN,
        Wih, Whh_h, bih, bhh, inp_acc + 2 * FEAT, sumexp + 2, h0, h1, c_state, Wbuf + 2 * HID);

    // E: gat1 || feat2
    k_stage<<<NB + FEAT_BLKS, 256, 33280, stream>>>(
        NB, 1, FEAT_BLKS,
        ccnt, coarse, al, ar, hfeat, out,
        node_embs + (size_t)2 * NN * FEAT, Wbuf + 2 * HID, att,
        hfeat + (size_t)2 * NN * FEAT, al + 2 * NN, ar + 2 * NN,
        Wih, Whh_h, bih, bhh, inp_acc + 2 * FEAT, sumexp + 2, h1, h0, c_state, Wbuf + 2 * HID);

    // F: gat2
    k_stage<<<NB, 256, 33280, stream>>>(
        NB, 2, 0,
        ccnt, coarse, al, ar, hfeat, out,
        node_embs, Wbuf, att, hfeat, al, ar,
        Wih, Whh_h, bih, bhh, inp_acc, sumexp, h1, h0, c_state, Wbuf);
}

// Round 12
// 343.423 us; speedup vs baseline: 1.4297x; 1.4297x over previous
//
#include <hip/hip_runtime.h>
#include <hip/hip_fp16.h>
#include <math.h>

#define NN 50000
#define NE 800000
#define FEAT 64
#define HID 4096
#define NEG_SLOPE 0.2f
#define T_STEPS 3
#define SLOTS 64                      // per-dst max in-degree (mean 16, P(>=64)~2e-18)
#define NB 391                        // coarse buckets per step: dst>>7
#define CAP 2560                      // per coarse-region capacity (mean 2048, ~11 sigma)
#define CHUNK 4096
#define CHUNKS_PER_STEP ((NE + CHUNK - 1) / CHUNK)   // 196
#define FEAT_BLKS ((NN + 255) / 256)

__device__ __forceinline__ int pack_half2(float a, float b) {
    __half2 h = __floats2half2_rn(a, b);
    return *(int*)&h;
}
__device__ __forceinline__ float2 unpack_half2(int v) {
    __half2 h = *(__half2*)&v;
    return __half22float2(h);
}

// h0 <- W0, c <- 0, inp_acc <- 0, sumexp <- 0, coarse_cnt <- 0
__global__ void k_init(const float* __restrict__ W0, float* __restrict__ h0, float* __restrict__ c,
                       float* __restrict__ inp_acc, float* __restrict__ sumexp,
                       int* __restrict__ coarse_cnt) {
    int i = blockIdx.x * blockDim.x + threadIdx.x;
    if (i < HID) { h0[i] = W0[i]; c[i] = 0.f; }
    if (i < T_STEPS * FEAT) inp_acc[i] = 0.f;
    if (i < T_STEPS) sumexp[i] = 0.f;
    if (i < T_STEPS * NB) coarse_cnt[i] = 0;
}

// ALL steps batched: inp_acc[t][f] += sum_n exp(mask)*x; sumexp[t] += sum_n exp(mask)
__global__ void k_wsum_all(const float* __restrict__ node_embs, const float* __restrict__ mask,
                           float* __restrict__ sumexp, float* __restrict__ inp_acc) {
    int t = blockIdx.x >> 8;
    int blk = blockIdx.x & 255;
    const float* x_t = node_embs + (size_t)t * NN * FEAT;
    const float* mask_t = mask + (size_t)t * NN;
    int lane = threadIdx.x & 63;
    int wib = threadIdx.x >> 6;
    int gw = blk * 4 + wib;
    float acc = 0.f, se = 0.f;
    for (int n = gw; n < NN; n += 1024) {
        float w = expf(mask_t[n]);
        acc += w * x_t[(size_t)n * FEAT + lane];
        se += w;
    }
    __shared__ float sacc[4][FEAT];
    sacc[wib][lane] = acc;
    __syncthreads();
    if (wib == 0)
        atomicAdd(&inp_acc[t * FEAT + lane],
                  sacc[0][lane] + sacc[1][lane] + sacc[2][lane] + sacc[3][lane]);
    if (lane == 0) atomicAdd(&sumexp[t], se);
}

// Fused gates+cell: one wave per unit u; rows {u,u+H,u+2H,u+3H}; CVT emits fp16 Whh copy
template <bool CVT>
__global__ __launch_bounds__(256) void k_lstm(
    const float* __restrict__ Wih, const float* __restrict__ Whh, __half* __restrict__ Whh_h,
    const float* __restrict__ bih, const float* __restrict__ bhh,
    const float* __restrict__ inp_acc_t, const float* __restrict__ sumexp_t,
    const float* __restrict__ h_old, float* __restrict__ h_new,
    float* __restrict__ c, float* __restrict__ Wbuf_t) {
    int lane = threadIdx.x & 63;
    int u = (blockIdx.x * blockDim.x + threadIdx.x) >> 6;
    if (u >= HID) return;
    float inp_l = inp_acc_t[lane] / (*sumexp_t);
    const float4* h4 = (const float4*)h_old;
    float g4[4];
    #pragma unroll
    for (int gi = 0; gi < 4; ++gi) {
        int row = u + gi * HID;
        float acc = 0.f;
        if (CVT) {
            const float4* wr = (const float4*)(Whh + (size_t)row * HID);
            int2* wh = (int2*)(Whh_h + (size_t)row * HID);
            #pragma unroll
            for (int cc = 0; cc < 16; ++cc) {
                float4 w = wr[cc * 64 + lane];
                float4 hv = h4[cc * 64 + lane];
                acc += w.x * hv.x + w.y * hv.y + w.z * hv.z + w.w * hv.w;
                int2 p;
                p.x = pack_half2(w.x, w.y);
                p.y = pack_half2(w.z, w.w);
                wh[cc * 64 + lane] = p;
            }
        } else {
            const int4* wr = (const int4*)(Whh_h + (size_t)row * HID);
            #pragma unroll
            for (int cc = 0; cc < 8; ++cc) {
                int4 w = wr[cc * 64 + lane];
                float2 wa = unpack_half2(w.x), wb = unpack_half2(w.y);
                float2 wc = unpack_half2(w.z), wd = unpack_half2(w.w);
                float4 hv0 = h4[(cc * 64 + lane) * 2];
                float4 hv1 = h4[(cc * 64 + lane) * 2 + 1];
                acc += wa.x * hv0.x + wa.y * hv0.y + wb.x * hv0.z + wb.y * hv0.w;
                acc += wc.x * hv1.x + wc.y * hv1.y + wd.x * hv1.z + wd.y * hv1.w;
            }
        }
        acc += Wih[(size_t)row * FEAT + lane] * inp_l;
        #pragma unroll
        for (int off = 32; off > 0; off >>= 1) acc += __shfl_xor(acc, off, 64);
        if (lane == 0) g4[gi] = acc + bih[row] + bhh[row];
    }
    if (lane == 0) {
        float si = 1.f / (1.f + expf(-g4[0]));
        float sf = 1.f / (1.f + expf(-g4[1]));
        float so = 1.f / (1.f + expf(-g4[3]));
        float c2 = sf * c[u] + si * tanhf(g4[2]);
        float h2 = so * tanhf(c2);
        c[u] = c2; h_new[u] = h2; Wbuf_t[u] = h2;
    }
}

// BATCHED: hfeat(fp16) = x @ W_t; al/ar = hfeat·att (fp32 pre-round)
__global__ __launch_bounds__(256) void k_feat_all(
    const float* __restrict__ node_embs, const float* __restrict__ Wbuf,
    const float* __restrict__ att, __half* __restrict__ hfeat,
    float* __restrict__ al, float* __restrict__ ar) {
    int t = blockIdx.x / FEAT_BLKS;
    int blk = blockIdx.x % FEAT_BLKS;
    __shared__ float Wl[HID];
    __shared__ float attS[2 * FEAT];
    for (int i = threadIdx.x; i < HID; i += 256) Wl[i] = Wbuf[t * HID + i];
    if (threadIdx.x < 2 * FEAT) attS[threadIdx.x] = att[threadIdx.x];
    __syncthreads();
    int n = blk * 256 + threadIdx.x;
    if (n >= NN) return;
    const float* x_t = node_embs + (size_t)t * NN * FEAT;
    float acc[FEAT];
    #pragma unroll
    for (int o = 0; o < FEAT; ++o) acc[o] = 0.f;
    const float4* x4 = (const float4*)(x_t + (size_t)n * FEAT);
    for (int k4 = 0; k4 < 16; ++k4) {
        float4 xv = x4[k4];
        const float* w0 = &Wl[(k4 * 4 + 0) * FEAT];
        const float* w1 = &Wl[(k4 * 4 + 1) * FEAT];
        const float* w2 = &Wl[(k4 * 4 + 2) * FEAT];
        const float* w3 = &Wl[(k4 * 4 + 3) * FEAT];
        #pragma unroll
        for (int o = 0; o < FEAT; ++o)
            acc[o] += xv.x * w0[o] + xv.y * w1[o] + xv.z * w2[o] + xv.w * w3[o];
    }
    float aL = 0.f, aR = 0.f;
    #pragma unroll
    for (int o = 0; o < FEAT; ++o) { aL += acc[o] * attS[o]; aR += acc[o] * attS[FEAT + o]; }
    size_t gn = (size_t)t * NN + n;
    int4* hf = (int4*)(hfeat + gn * FEAT);
    #pragma unroll
    for (int i = 0; i < 8; ++i) {
        int4 v;
        v.x = pack_half2(acc[8 * i + 0], acc[8 * i + 1]);
        v.y = pack_half2(acc[8 * i + 2], acc[8 * i + 3]);
        v.z = pack_half2(acc[8 * i + 4], acc[8 * i + 5]);
        v.w = pack_half2(acc[8 * i + 6], acc[8 * i + 7]);
        hf[i] = v;
    }
    al[gn] = aL; ar[gn] = aR;
}

// Coarse counting-sort pass: chunk of 4096 edges -> LDS-sorted by cb=dst>>7 -> coalesced flush.
__global__ __launch_bounds__(256) void k_part(
    const int* __restrict__ edge_index, const float* __restrict__ edge_weight,
    int* __restrict__ coarse_cnt, int2* __restrict__ coarse) {
    int t = blockIdx.x / CHUNKS_PER_STEP;
    int ch = blockIdx.x % CHUNKS_PER_STEP;
    int e0 = ch * CHUNK;
    int eN = (e0 + CHUNK <= NE) ? CHUNK : (NE - e0);
    const int* src = edge_index + (size_t)t * 2 * NE;
    const int* dst = src + NE;
    const float* ew = edge_weight + (size_t)t * NE;
    int tid = threadIdx.x;

    __shared__ int hist[NB], offs[NB], baseg[NB], cursor[NB];
    __shared__ int sc[256];
    __shared__ int2 stag[CHUNK];

    for (int i = tid; i < NB; i += 256) hist[i] = 0;
    __syncthreads();
    for (int k = tid; k < eN; k += 256) atomicAdd(&hist[dst[e0 + k] >> 7], 1);
    __syncthreads();
    int a0 = (2 * tid < NB) ? hist[2 * tid] : 0;
    int a1 = (2 * tid + 1 < NB) ? hist[2 * tid + 1] : 0;
    sc[tid] = a0 + a1;
    __syncthreads();
    for (int off = 1; off < 256; off <<= 1) {
        int v = (tid >= off) ? sc[tid - off] : 0;
        __syncthreads();
        sc[tid] += v;
        __syncthreads();
    }
    int excl = (tid == 0) ? 0 : sc[tid - 1];
    if (2 * tid < NB)     { offs[2 * tid] = excl;          cursor[2 * tid] = excl; }
    if (2 * tid + 1 < NB) { offs[2 * tid + 1] = excl + a0; cursor[2 * tid + 1] = excl + a0; }
    __syncthreads();
    for (int k = tid; k < eN; k += 256) {
        int d = dst[e0 + k], s = src[e0 + k];
        float wv = ew[e0 + k];
        int cb = d >> 7, doff = d & 127;
        int p = atomicAdd(&cursor[cb], 1);
        stag[p] = make_int2(s | (doff << 16) | (cb << 23), __float_as_int(wv));
    }
    __syncthreads();
    for (int cb = tid; cb < NB; cb += 256) {
        int cnum = hist[cb];
        baseg[cb] = cnum ? atomicAdd(&coarse_cnt[t * NB + cb], cnum) : 0;
    }
    __syncthreads();
    for (int j = tid; j < eN; j += 256) {
        int2 r = stag[j];
        int cb = ((unsigned)r.x) >> 23;
        int gpos = baseg[cb] + (j - offs[cb]);
        if (gpos < CAP)
            coarse[((size_t)(t * NB + cb)) * CAP + gpos] = r;
    }
}

// Fused fine-bin + GAT: block per (t,cb) owns 128 dst rows; fine slots in LDS.
// Inner loop: 8 edges in flight per wave (8 subgroups x 8 lanes x 8 features, int4 reads).
__global__ __launch_bounds__(512) void k_gat(
    const int* __restrict__ coarse_cnt, const int2* __restrict__ coarse,
    const float* __restrict__ al, const float* __restrict__ ar,
    const __half* __restrict__ hfeat, float* __restrict__ out) {
    int t = blockIdx.x / NB;
    int cb = blockIdx.x % NB;
    int n0 = cb << 7;
    int tid = threadIdx.x;
    __shared__ int fine[128 * SLOTS];
    __shared__ int fcnt[128];
    for (int i = tid; i < 128; i += 512) fcnt[i] = 0;
    __syncthreads();
    int m = coarse_cnt[t * NB + cb];
    if (m > CAP) m = CAP;
    const int2* reg = coarse + ((size_t)(t * NB + cb)) * CAP;
    for (int k = tid; k < m; k += 512) {
        int2 r = reg[k];
        int doff = (r.x >> 16) & 127;
        int p = atomicAdd(&fcnt[doff], 1);
        if (p < SLOTS) {
            unsigned int eh = (unsigned int)__half_as_ushort(__float2half_rn(__int_as_float(r.y)));
            fine[doff * SLOTS + p] = (r.x & 0xffff) | (int)(eh << 16);
        }
    }
    __syncthreads();
    int lane = tid & 63, w = tid >> 6;          // 8 waves
    const float* al_t = al + (size_t)t * NN;
    const __half* hf_t = hfeat + (size_t)t * NN * FEAT;
    int sub = lane >> 3;                        // 8 subgroups of 8 lanes
    int fl = (lane & 7) * 8;                    // 8 features per lane
    for (int doff = w; doff < 128; doff += 8) {
        int row = n0 + doff;
        if (row >= NN) break;
        int cn = fcnt[doff]; if (cn > SLOTS) cn = SLOTS;
        float ard = ar[(size_t)t * NN + row];
        float acc[8];
        #pragma unroll
        for (int q = 0; q < 8; ++q) acc[q] = 0.f;
        float psum = 0.f;
        for (int i = sub; i < cn; i += 8) {
            int r = fine[doff * SLOTS + i];
            int s = r & 0xffff;
            float ewv = __half2float(__ushort_as_half((unsigned short)((unsigned int)r >> 16)));
            float e = al_t[s] + ard;
            e = e >= 0.f ? e : NEG_SLOPE * e;
            float p = expf(e);
            psum += p;
            float pe = p * ewv;
            int4 hv = *(const int4*)(hf_t + (size_t)s * FEAT + fl);   // 8 halves = 16B
            float2 h0 = unpack_half2(hv.x), h1 = unpack_half2(hv.y);
            float2 h2 = unpack_half2(hv.z), h3 = unpack_half2(hv.w);
            acc[0] += pe * h0.x; acc[1] += pe * h0.y;
            acc[2] += pe * h1.x; acc[3] += pe * h1.y;
            acc[4] += pe * h2.x; acc[5] += pe * h2.y;
            acc[6] += pe * h3.x; acc[7] += pe * h3.y;
        }
        // reduce across the 8 subgroups: lanes l, l^8, l^16, l^32 own the same features
        #pragma unroll
        for (int off = 8; off <= 32; off <<= 1) {
            #pragma unroll
            for (int q = 0; q < 8; ++q) acc[q] += __shfl_xor(acc[q], off, 64);
            psum += __shfl_xor(psum, off, 64);
        }
        float inv = 1.f / (psum + 1e-16f);
        if (sub == 0) {
            float* op = out + ((size_t)t * NN + row) * FEAT + fl;
            *(float4*)op       = make_float4(acc[0] * inv, acc[1] * inv, acc[2] * inv, acc[3] * inv);
            *(float4*)(op + 4) = make_float4(acc[4] * inv, acc[5] * inv, acc[6] * inv, acc[7] * inv);
        }
    }
}

extern "C" void kernel_launch(void* const* d_in, const int* in_sizes, int n_in,
                              void* d_out, int out_size, void* d_ws, size_t ws_size,
                              hipStream_t stream) {
    const float* node_embs   = (const float*)d_in[0];
    const float* mask        = (const float*)d_in[1];
    const int*   edge_index  = (const int*)d_in[2];
    const float* edge_weight = (const float*)d_in[3];
    const float* Wih         = (const float*)d_in[4];
    const float* Whh         = (const float*)d_in[5];
    const float* bih         = (const float*)d_in[6];
    const float* bhh         = (const float*)d_in[7];
    const float* W0          = (const float*)d_in[8];
    const float* att         = (const float*)d_in[9];
    float* out = (float*)d_out;
    float* ws  = (float*)d_ws;

    // workspace layout (4B units), total ~180 MB
    float*  h0       = ws;                         // 4096
    float*  h1       = ws + 4096;                  // 4096
    float*  c_state  = ws + 8192;                  // 4096
    float*  sumexp   = ws + 12288;                 // 3 (+pad)
    float*  inp_acc  = ws + 12292;                 // 192
    float*  Wbuf     = ws + 12544;                 // 3*4096
    float*  al       = ws + 24832;                 // 3*50000
    float*  ar       = ws + 174832;                // 3*50000
    int*    ccnt     = (int*)(ws + 324832);        // 3*NB (+pad to 326016)
    int2*   coarse   = (int2*)(ws + 326016);       // 3*NB*CAP int2 = 24 MB
    __half* Whh_h    = (__half*)(ws + 6331776);    // 67.1M halves = 128 MB
    __half* hfeat    = (__half*)(ws + 39886208);   // 9.6M halves = 19.2 MB

    k_init<<<16, 256, 0, stream>>>(W0, h0, c_state, inp_acc, sumexp, ccnt);
    k_wsum_all<<<T_STEPS * 256, 256, 0, stream>>>(node_embs, mask, sumexp, inp_acc);

    // LSTM chain: ping-pong h; t=0 emits fp16 Whh
    float* hc = h0;
    for (int t = 0; t < T_STEPS; ++t) {
        float* hn = (hc == h0) ? h1 : h0;
        if (t == 0)
            k_lstm<true><<<HID / 4, 256, 0, stream>>>(Wih, Whh, Whh_h, bih, bhh,
                                                      inp_acc + t * FEAT, sumexp + t,
                                                      hc, hn, c_state, Wbuf + (size_t)t * HID);
        else
            k_lstm<false><<<HID / 4, 256, 0, stream>>>(Wih, Whh, Whh_h, bih, bhh,
                                                       inp_acc + t * FEAT, sumexp + t,
                                                       hc, hn, c_state, Wbuf + (size_t)t * HID);
        hc = hn;
    }

    // Batched GAT across all 3 steps
    k_feat_all<<<T_STEPS * FEAT_BLKS, 256, 0, stream>>>(node_embs, Wbuf, att, hfeat, al, ar);
    k_part<<<T_STEPS * CHUNKS_PER_STEP, 256, 0, stream>>>(edge_index, edge_weight, ccnt, coarse);
    k_gat<<<T_STEPS * NB, 512, 0, stream>>>(ccnt, coarse, al, ar, hfeat, out);
}